// Round 6
// baseline (115.598 us; speedup 1.0000x reference)
//
#include <hip/hip_runtime.h>
#include <hip/hip_bf16.h>
#include <math.h>

// Problem: B=4, L=2048 (M = 8192 rows), D_MODEL = 768, N_STATE = 16.
// y[row,d] = x[row,d] * softplus((x@W1+b1)[row,d]) * dot(x@W2+b2, x@W3+b3)[row]
// (dA*h0 term is identically zero; A unused.)
// Ledger: ~47 us harness fills per iter (fixed). R10: direct-from-global GEMM
// loses 2x. R11 (112.1): xb precompute + single-buffer async16 k-loop. R12-R15:
// cvt-in-gemm/reg-pipelines all regressed (compiler sinks or spills reg
// staging). R16: 2x occupancy at 64x64 = null -> stall is NOT TLP-hideable;
// it's the naked per-step drain (stage issued then immediately drained before
// compute; m233's ~72% 2-phase overhead). R17 (this round): minimal T3 —
// dbuf LDS, stage(t+1) issued BEFORE compute(t), ONE vmcnt(0)+s_barrier per
// step placed AFTER compute. Zero-register staging (async16) -> no spill
// risk. W frags global->reg (w23t L2-hot; verified R13/R15). 49 KB LDS ->
// 3 blocks/CU.

#define M_ROWS 8192
#define DM 768
#define NS 16
#define NT 12   // k-steps: 768 / 64

typedef short bf16x8 __attribute__((ext_vector_type(8)));
typedef float f32x4 __attribute__((ext_vector_type(4)));

__device__ __forceinline__ unsigned short f2bf(float f) {
    union { float f; unsigned u; } v; v.f = f;
    unsigned r = v.u + 0x7FFF + ((v.u >> 16) & 1);   // RNE
    return (unsigned short)(r >> 16);
}
__device__ __forceinline__ float bf2f(unsigned short h) {
    union { unsigned u; float f; } v; v.u = ((unsigned)h) << 16; return v.f;
}
__device__ __forceinline__ void async16(const void* g, void* l) {
    __builtin_amdgcn_global_load_lds(
        (const __attribute__((address_space(1))) void*)g,
        (__attribute__((address_space(3))) void*)l,
        16, 0, 0);
}
// branchless stable softplus: max(v,0) + log(1+exp(-|v|)); HW exp/log.
__device__ __forceinline__ float softplus_fast(float v) {
    return fmaxf(v, 0.f) + __logf(1.f + __expf(-fabsf(v)));
}

#define FENCE() __builtin_amdgcn_sched_barrier(0)

// ---- kernel 1: prep (pure streaming, block-specialized) -----------------
// bid [0,32):      w23t build (bf16 n-major, pair-interleaved W2/W3 cols).
// bid [32,608):    W1 [k][n] fp32 -> w1t [n][k] bf16 (32x32 LDS tiles).
// bid [608,6752):  streaming convert x -> xb (bf16), float4/thread.
__global__ __launch_bounds__(256) void prep_kernel(
    const float* __restrict__ x,
    const float* __restrict__ W1,
    const float* __restrict__ W2,
    const float* __restrict__ W3,
    unsigned short* __restrict__ xb,
    unsigned short* __restrict__ w1t,
    unsigned short* __restrict__ w23t)
{
    __shared__ float tile[32][33];
    const int bid = blockIdx.x;
    const int tid = threadIdx.x;
    if (bid < 32) {
        const int n = bid, i = n >> 1;
        const float* src = (n & 1) ? W3 : W2;
        #pragma unroll
        for (int e = 0; e < 3; ++e) {
            int k = e * 256 + tid;
            w23t[n * DM + k] = f2bf(src[k * NS + i]);
        }
    } else if (bid < 608) {
        const int b2i = bid - 32;                // 0..575
        const int n0 = (b2i % 24) * 32, k0 = (b2i / 24) * 32;
        const int tx = tid & 31, ty = tid >> 5;  // 32 x 8
        #pragma unroll
        for (int i = 0; i < 4; ++i) {
            int k = ty + i * 8;
            tile[k][tx] = W1[(k0 + k) * DM + n0 + tx];
        }
        __syncthreads();
        #pragma unroll
        for (int i = 0; i < 4; ++i) {
            int n = ty + i * 8;
            w1t[(n0 + n) * DM + k0 + tx] = f2bf(tile[tx][n]);
        }
    } else {
        int i = (bid - 608) * 256 + tid;         // one float4 per thread
        float4 v = ((const float4*)x)[i];
        ushort4 o;
        o.x = f2bf(v.x); o.y = f2bf(v.y); o.z = f2bf(v.z); o.w = f2bf(v.w);
        ((ushort4*)xb)[i] = o;
    }
}

// ---- kernel 2: dbuf-pipelined GEMM + integrated s + softplus epilogue ---
// Per iter t (cur=t&1, nxt=cur^1):
//   S1: async16 stage A(t+1),B(t+1) -> buf[nxt]; LOAD_W(t+1) -> vw[nxt]
//   S2: compute(t) on Al[cur]/Bl[cur]/vw[cur]  (covers S1's latency)
//   S3: s_waitcnt vmcnt(0) lgkmcnt(0); s_barrier   (drains 1-phase-old S1)
// Race sweep: S1 writes buf[nxt] only; S2 reads buf[cur] only; barrier at
// iter end separates all buf[cur] reads from iter t+1's stage into buf[cur].
// All barriers wave-uniform (loop bounds compile-time).
__global__ __launch_bounds__(256) void gemm_fused_kernel(
    const unsigned short* __restrict__ xb,    // [8192][768] bf16
    const unsigned short* __restrict__ w1t,   // [768][768] bf16, n-major
    const unsigned short* __restrict__ w23t,  // [32][768] bf16, pair-interleaved
    const float* __restrict__ b1,
    const float* __restrict__ b2, const float* __restrict__ b3,
    float* __restrict__ y)
{
    __shared__ unsigned short Al[2][128 * 64];   // 32 KB
    __shared__ unsigned short Bl[2][64 * 64];    // 16 KB
    __shared__ float spart[2][128];              //  1 KB
    const int b = blockIdx.x;
    const int c = b & 7, j = b >> 3;          // j in [0,96)
    const int m0 = (c * 8 + j / 12) * 128;
    const int n0 = (j % 12) * 64;
    const int tid  = threadIdx.x;
    const int lane = tid & 63;
    const int wave = tid >> 6;
    const int wm = wave >> 1, wn = wave & 1;
    const int l15 = lane & 15, quad = lane >> 4;

    f32x4 acc[4][2];
    f32x4 accP[4];
    #pragma unroll
    for (int i = 0; i < 4; ++i) {
        accP[i] = (f32x4){0.f, 0.f, 0.f, 0.f};
        #pragma unroll
        for (int jj = 0; jj < 2; ++jj)
            acc[i][jj] = (f32x4){0.f, 0.f, 0.f, 0.f};
    }

    bf16x8 vw[2][2];     // W23 fragments, [parity][kk], one k-step ahead

#define STAGE_AB(P, T) do {                                                \
        const int k0_ = (T) * 64;                                          \
        _Pragma("unroll")                                                  \
        for (int i_ = 0; i_ < 4; ++i_) {      /* A: 1024 chunks */         \
            int ch_ = tid + i_ * 256;                                      \
            int r_ = ch_ >> 3, jg_ = (ch_ & 7) ^ (r_ & 7);                 \
            async16(xb + (m0 + r_) * DM + k0_ + jg_ * 8, &Al[P][ch_ * 8]); \
        }                                                                  \
        _Pragma("unroll")                                                  \
        for (int i_ = 0; i_ < 2; ++i_) {      /* B: 512 chunks */          \
            int ch_ = tid + i_ * 256;                                      \
            int r_ = ch_ >> 3, jg_ = (ch_ & 7) ^ (r_ & 7);                 \
            async16(w1t + (n0 + r_) * DM + k0_ + jg_ * 8, &Bl[P][ch_ * 8]); \
        }                                                                  \
    } while (0)

#define LOAD_W(P, T) do {                                                  \
        const int k0_ = (T) * 64;                                          \
        const int rw_ = wn * 16 + l15;                                     \
        _Pragma("unroll")                                                  \
        for (int kk_ = 0; kk_ < 2; ++kk_)                                  \
            vw[P][kk_] = *(const bf16x8*)(w23t + rw_ * DM + k0_ + (kk_ * 4 + quad) * 8); \
    } while (0)

    // ---- prologue: stage t=0 ----
    STAGE_AB(0, 0);
    LOAD_W(0, 0);
    FENCE();
    asm volatile("s_waitcnt vmcnt(0) lgkmcnt(0)" ::: "memory");
    __builtin_amdgcn_s_barrier();
    FENCE();

    // ---- main loop: prefetch -> compute -> single drain+barrier ----
    #pragma unroll
    for (int t = 0; t < NT; ++t) {
        const int cur = t & 1;
        // S1: issue stage for t+1 into the other buffer (no drain here)
        if (t + 1 < NT) {
            STAGE_AB(cur ^ 1, t + 1);
            LOAD_W(cur ^ 1, t + 1);
        }
        FENCE();
        // S2: compute(t) — covers S1's latency
        #pragma unroll
        for (int kk = 0; kk < 2; ++kk) {
            bf16x8 bfr[2];
            #pragma unroll
            for (int jj = 0; jj < 2; ++jj) {
                int rb = wn * 32 + jj * 16 + l15;
                int jb = (kk * 4 + quad) ^ (rb & 7);
                bfr[jj] = *(const bf16x8*)(&Bl[cur][rb * 64 + jb * 8]);
            }
            bf16x8 wfr = vw[cur][kk];
            #pragma unroll
            for (int i = 0; i < 4; ++i) {
                int rr = wm * 64 + i * 16 + l15;
                int ja = (kk * 4 + quad) ^ (rr & 7);
                bf16x8 af = *(const bf16x8*)(&Al[cur][rr * 64 + ja * 8]);
                #pragma unroll
                for (int jj = 0; jj < 2; ++jj)
                    acc[i][jj] = __builtin_amdgcn_mfma_f32_16x16x32_bf16(
                        af, bfr[jj], acc[i][jj], 0, 0, 0);
                accP[i] = __builtin_amdgcn_mfma_f32_16x16x32_bf16(
                    af, wfr, accP[i], 0, 0, 0);
            }
        }
        FENCE();
        // S3: single drain (1-phase-old loads) + barrier
        asm volatile("s_waitcnt vmcnt(0) lgkmcnt(0)" ::: "memory");
        __builtin_amdgcn_s_barrier();
        FENCE();
    }

    // ---- s partials: this wave owns pairs p = wn*8 + (l15>>1) ----
    {
        const int p = wn * 8 + (l15 >> 1);
        const float bB = b2[p], bC = b3[p];
        #pragma unroll
        for (int i = 0; i < 4; ++i) {
            float sacc[4];
            #pragma unroll
            for (int r = 0; r < 4; ++r) {
                float v = accP[i][r];
                float pv = __shfl_xor(v, 1, 64);
                sacc[r] = (l15 & 1) ? (pv + bB) * (v + bC)
                                    : (v + bB) * (pv + bC);
                sacc[r] += __shfl_xor(sacc[r], 1, 64);
                sacc[r] += __shfl_xor(sacc[r], 2, 64);
                sacc[r] += __shfl_xor(sacc[r], 4, 64);
                sacc[r] += __shfl_xor(sacc[r], 8, 64);
            }
            if (l15 == 0) {
                #pragma unroll
                for (int r = 0; r < 4; ++r)
                    spart[wn][wm * 64 + i * 16 + quad * 4 + r] = 0.5f * sacc[r];
            }
        }
    }
    __syncthreads();

    // ---- epilogue: C/D layout col = lane&15, row = quad*4 + reg ----
    #pragma unroll
    for (int i = 0; i < 4; ++i) {
        const int rl = wm * 64 + i * 16 + quad * 4;   // local row base
        const int rowbase = m0 + rl;
        float sv4[4];
        #pragma unroll
        for (int r = 0; r < 4; ++r)
            sv4[r] = spart[0][rl + r] + spart[1][rl + r];
        #pragma unroll
        for (int jj = 0; jj < 2; ++jj) {
            int gcol = n0 + wn * 32 + jj * 16 + l15;
            float bias = b1[gcol];
            #pragma unroll
            for (int r = 0; r < 4; ++r) {
                int grow = rowbase + r;
                float v = acc[i][jj][r] + bias;
                float sp = softplus_fast(v);
                float xv = bf2f(xb[grow * DM + gcol]);
                y[grow * DM + gcol] = xv * sp * sv4[r];
            }
        }
    }
#undef STAGE_AB
#undef LOAD_W
}

extern "C" void kernel_launch(void* const* d_in, const int* in_sizes, int n_in,
                              void* d_out, int out_size, void* d_ws, size_t ws_size,
                              hipStream_t stream) {
    const float* x  = (const float*)d_in[0];
    const float* W1 = (const float*)d_in[1];
    const float* b1 = (const float*)d_in[2];
    const float* W2 = (const float*)d_in[3];
    const float* b2 = (const float*)d_in[4];
    const float* W3 = (const float*)d_in[5];
    const float* b3 = (const float*)d_in[6];
    // d_in[7] = A : unused (multiplied by h0 == 0 in the reference)
    float* y = (float*)d_out;

    unsigned short* xb   = (unsigned short*)d_ws;                      // 12,582,912 B
    unsigned short* w1t  = (unsigned short*)((char*)d_ws + 12582912);  //  1,179,648 B
    unsigned short* w23t = (unsigned short*)((char*)d_ws + 13762560);  //     49,152 B

    prep_kernel<<<6752, 256, 0, stream>>>(x, W1, W2, W3, xb, w1t, w23t);
    gemm_fused_kernel<<<768, 256, 0, stream>>>(xb, w1t, w23t, b1, b2, b3, y);
}